// Round 2
// baseline (276.528 us; speedup 1.0000x reference)
//
#include <hip/hip_runtime.h>
#include <math.h>

#define BB 16
#define QQ 900
#define CC 92
#define NP 32
#define TT (BB*NP)   // 512

// ---------------------------------------------------------------------------
// Zero the output (harness poisons d_out with 0xAA before every timed call).
__global__ void zero_out_kernel(float4* __restrict__ out) {
    int i = blockIdx.x * blockDim.x + threadIdx.x;
    if (i < (QQ * TT) / 4) out[i] = make_float4(0.f, 0.f, 0.f, 0.f);
}

// ---------------------------------------------------------------------------
// One workgroup per batch block b. Replicates the REFERENCE's _lsa exactly:
// NOTE the reference is NOT textbook JV — `mv = minv.copy()` means minv never
// absorbs `cur`; it only accumulates -delta. delta = min over unused of
// min(minv_old, cur) and may be NEGATIVE. way[j] is set whenever cur<minv_old.
// We replicate those semantics verbatim in fp64.
__launch_bounds__(256)
__global__ void matcher_kernel(const float* __restrict__ logits,   // (B,Q,C)
                               const float* __restrict__ pboxes,   // (B,Q,4)
                               const int*   __restrict__ labels,   // (T,)
                               const float* __restrict__ tboxes,   // (T,4)
                               float* __restrict__ costws,         // (B,NP,Q)
                               float* __restrict__ out)            // (Q,T)
{
    const int b   = blockIdx.x;
    const int tid = threadIdx.x;

    __shared__ float  s_max[QQ];
    __shared__ float  s_sum[QQ];
    __shared__ double s_minv[QQ + 1];
    __shared__ double s_v[QQ + 1];
    __shared__ double s_u[NP + 1];
    __shared__ int    s_p[QQ + 1];
    __shared__ int    s_way[QQ + 1];
    __shared__ unsigned char s_used[QQ + 1];
    __shared__ double s_rv[4];
    __shared__ int    s_ri[4];
    __shared__ int    s_j0;
    __shared__ int    s_i0;
    __shared__ double s_ui0;
    __shared__ double s_delta;

    // ---- 1. softmax denominators ------------------------------------------
    const float* lg = logits + (size_t)b * QQ * CC;
    for (int q = tid; q < QQ; q += 256) {
        const float* row = lg + q * CC;
        float mx = -INFINITY;
        for (int c = 0; c < CC; ++c) mx = fmaxf(mx, row[c]);
        float s = 0.f;
        for (int c = 0; c < CC; ++c) s += expf(row[c] - mx);
        s_max[q] = mx;
        s_sum[q] = s;
    }
    __syncthreads();

    // ---- 2. cost matrix C^T[t][q] -----------------------------------------
    const float* pb = pboxes + (size_t)b * QQ * 4;
    const float* tb = tboxes + (size_t)b * NP * 4;
    const int*   lb = labels + b * NP;
    float* cw = costws + (size_t)b * NP * QQ;
    for (int idx = tid; idx < NP * QQ; idx += 256) {
        int t = idx / QQ;
        int q = idx - t * QQ;
        // class cost
        float l    = lg[q * CC + lb[t]];
        float prob = expf(l - s_max[q]) / s_sum[q];
        float cclass = -prob;
        // bbox L1
        float p0 = pb[q*4+0], p1 = pb[q*4+1], p2 = pb[q*4+2], p3 = pb[q*4+3];
        float t0 = tb[t*4+0], t1 = tb[t*4+1], t2 = tb[t*4+2], t3 = tb[t*4+3];
        float cbbox = fabsf(p0-t0) + fabsf(p1-t1) + fabsf(p2-t2) + fabsf(p3-t3);
        // GIoU (cxcywh -> xyxy, mirroring the reference op order)
        float px1 = p0 - 0.5f*p2, py1 = p1 - 0.5f*p3;
        float px2 = p0 + 0.5f*p2, py2 = p1 + 0.5f*p3;
        float tx1 = t0 - 0.5f*t2, ty1 = t1 - 0.5f*t3;
        float tx2 = t0 + 0.5f*t2, ty2 = t1 + 0.5f*t3;
        float area1 = (px2-px1)*(py2-py1);
        float area2 = (tx2-tx1)*(ty2-ty1);
        float ltx = fmaxf(px1,tx1), lty = fmaxf(py1,ty1);
        float rbx = fminf(px2,tx2), rby = fminf(py2,ty2);
        float wx = fmaxf(rbx-ltx, 0.f), wy = fmaxf(rby-lty, 0.f);
        float inter = wx*wy;
        float uni = area1 + area2 - inter;
        float iou = inter / uni;
        float cx1 = fminf(px1,tx1), cy1 = fminf(py1,ty1);
        float cx2 = fmaxf(px2,tx2), cy2 = fmaxf(py2,ty2);
        float cwx = fmaxf(cx2-cx1, 0.f), cwy = fmaxf(cy2-cy1, 0.f);
        float areac = cwx*cwy;
        float giou = iou - (areac - uni) / areac;
        cw[idx] = 5.f*cbbox + 1.f*cclass + 2.f*(-giou);
    }

    // ---- 3. reference-_lsa assignment (rows = 32 targets, cols = 900) -----
    for (int j = tid; j <= QQ; j += 256) { s_v[j] = 0.0; s_p[j] = 0; }
    if (tid <= NP) s_u[tid] = 0.0;
    __syncthreads();

    const int lane = tid & 63;
    const int wv   = tid >> 6;

    for (int i = 1; i <= NP; ++i) {
        for (int j = tid; j <= QQ; j += 256) { s_minv[j] = 1e18; s_used[j] = 0; }
        if (tid == 0) { s_p[0] = i; s_j0 = 0; }
        __syncthreads();

        for (int it = 0; it < QQ + 2; ++it) {
            if (tid == 0) {
                int j0 = s_j0;
                s_used[j0] = 1;
                int i0 = s_p[j0];
                s_i0  = i0;
                s_ui0 = s_u[i0];
            }
            __syncthreads();
            const int    j0  = s_j0;
            const int    i0  = s_i0;
            const double ui0 = s_ui0;
            const float* crow = costws + ((size_t)b * NP + (i0 - 1)) * QQ;

            // argmin over masked(mv) where mv = min(minv_old, cur) for unused.
            // CRITICAL: mv is TRANSIENT (reference's `.copy()`); minv itself
            // only ever gets -delta below.
            double bv = 1e300;
            int    bi = 0x7fffffff;
            #pragma unroll
            for (int k = 0; k < 4; ++k) {
                int j = 1 + tid + k * 256;
                if (j <= QQ && !s_used[j]) {
                    double cur = (double)crow[j - 1] - ui0 - s_v[j];
                    double old = s_minv[j];
                    double mval;
                    if (cur < old) { s_way[j] = j0; mval = cur; }
                    else           { mval = old; }
                    if (mval < bv) { bv = mval; bi = j; }  // increasing j -> first occurrence
                }
            }
            // wave64 (val,idx) argmin, prefer lower index on equality
            #pragma unroll
            for (int off = 32; off > 0; off >>= 1) {
                double ov = __shfl_down(bv, off, 64);
                int    oi = __shfl_down(bi, off, 64);
                if (ov < bv || (ov == bv && oi < bi)) { bv = ov; bi = oi; }
            }
            if (lane == 0) { s_rv[wv] = bv; s_ri[wv] = bi; }
            __syncthreads();
            if (tid == 0) {
                double dv = s_rv[0]; int di = s_ri[0];
                #pragma unroll
                for (int w = 1; w < 4; ++w)
                    if (s_rv[w] < dv || (s_rv[w] == dv && s_ri[w] < di)) { dv = s_rv[w]; di = s_ri[w]; }
                s_delta = dv;
                s_j0    = di;
            }
            __syncthreads();
            const double delta = s_delta;   // may be negative — reference quirk
            for (int j = tid; j <= QQ; j += 256) {
                if (s_used[j]) { s_u[s_p[j]] += delta; s_v[j] -= delta; }  // p distinct over used
                else if (j >= 1) { s_minv[j] -= delta; }                   // minv[0] untouched (ref)
            }
            __syncthreads();
            if (s_p[s_j0] == 0) break;   // uniform read after barrier
        }

        if (tid == 0) {  // augmenting-path flip (reverse chain of visited j0s)
            int j0 = s_j0;
            while (j0) { int j1 = s_way[j0]; s_p[j0] = s_p[j1]; j0 = j1; }
        }
        __syncthreads();
    }

    // ---- 4. scatter the 32 ones ------------------------------------------
    for (int j = 1 + tid; j <= QQ; j += 256) {
        int t = s_p[j] - 1;
        if (t >= 0) out[(size_t)(j - 1) * TT + b * NP + t] = 1.0f;
    }
}

// ---------------------------------------------------------------------------
extern "C" void kernel_launch(void* const* d_in, const int* in_sizes, int n_in,
                              void* d_out, int out_size, void* d_ws, size_t ws_size,
                              hipStream_t stream) {
    const float* logits = (const float*)d_in[0];   // (16,900,92)
    const float* pboxes = (const float*)d_in[1];   // (16,900,4)
    const int*   labels = (const int*)  d_in[2];   // (512,)
    const float* tboxes = (const float*)d_in[3];   // (512,4)
    float* out    = (float*)d_out;                 // (900,512) fp32
    float* costws = (float*)d_ws;                  // 16*32*900 floats = 1.84 MB

    zero_out_kernel<<<(QQ * TT / 4 + 255) / 256, 256, 0, stream>>>((float4*)out);
    matcher_kernel<<<BB, 256, 0, stream>>>(logits, pboxes, labels, tboxes, costws, out);
}